// Round 6
// baseline (233.403 us; speedup 1.0000x reference)
//
#include <hip/hip_runtime.h>

// change[i] (i>=1) ∝ (g(i-3) - g(i+2))^2   with g(k)=f[k] zero-padded; change[0]=0
// out[i] = (1 - change[i]/S)^5 * f[i],  S = sum(change)
// The 1/5 conv scaling cancels in change[i]/S, so we accumulate unscaled d^2.
//
// R11: SINGLE dispatch with a hand-rolled device barrier.
// Evidence: R8 showed measured ~= kernel-chain time (fills outside window);
// R9 showed reduce+gap = 86.5us with reduce <= 42 -> inter-dispatch gap >= 44us.
// The ~120us band of the 2-dispatch structure is therefore dominated by ONE
// dispatch-boundary gap, not kernel time. R8's cg::grid_sync cost ~200us
// (system-scope heavyweight barrier, 2048 blocks); replace it with:
//  - arrival: thread 0 per block, agent-scope release fetch_add on a
//    __device__ monotonic counter (generation trick -> no zero-init, no ws).
//  - spin: thread 0 only, acquire load + s_sleep backoff; block parked at
//    __syncthreads.
//  - partials: __device__ array, agent-scope atomic stores/loads
//    (poison-immune: every slot rewritten each iteration; release/acquire
//    chain gives cross-XCD visibility).
//  - deadlock insurance: bounded spin -> block recomputes S from f itself
//    (always correct; converts any co-residency failure into slowness).
// Phases are R10's proven lane-contiguous loops (per-instruction coalescing).

#define BLOCK 256
#define GRID_CAP 2048

typedef __attribute__((ext_vector_type(4))) float vfloat4;

__device__ unsigned int g_arrive = 0u;        // monotonic across graph replays
__device__ float g_partials[GRID_CAP];

__device__ __forceinline__ float change_term(const float* __restrict__ f, long long i, long long n) {
    if (i < 1) return 0.0f;
    float a = (i >= 3)    ? f[i - 3] : 0.0f;
    float b = (i + 2 < n) ? f[i + 2] : 0.0f;
    float d = a - b;
    return d * d;
}

__device__ __forceinline__ float pow5(float t) {
    float t2 = t * t;
    float t4 = t2 * t2;
    return t4 * t;
}

// terms for vector v given p=fv[v-1], c=fv[v], q=fv[v+1]; element j=4v+k uses
// a=f[j-3], b=f[j+2]
__device__ __forceinline__ float vec_terms(float4 p, float4 c, float4 q) {
    float d0 = p.y - c.z;
    float d1 = p.z - c.w;
    float d2 = p.w - q.x;
    float d3 = c.x - q.y;
    return d0 * d0 + d1 * d1 + d2 * d2 + d3 * d3;
}

__device__ __forceinline__ vfloat4 vec_out(float4 p, float4 c, float4 q, float inv) {
    float d0 = p.y - c.z;
    float d1 = p.z - c.w;
    float d2 = p.w - q.x;
    float d3 = c.x - q.y;
    vfloat4 o;
    o.x = pow5(1.0f - d0 * d0 * inv) * c.x;
    o.y = pow5(1.0f - d1 * d1 * inv) * c.y;
    o.z = pow5(1.0f - d2 * d2 * inv) * c.z;
    o.w = pow5(1.0f - d3 * d3 * inv) * c.w;
    return o;
}

__global__ __launch_bounds__(BLOCK)
void fused_onepass(const float* __restrict__ f, int nvec, long long n,
                   float* __restrict__ out) {
    const float4* __restrict__ fv = (const float4*)f;
    vfloat4* __restrict__ ov = (vfloat4*)out;
    const int grid = (int)gridDim.x;
    const int T = grid * BLOCK;
    const int tid = blockIdx.x * BLOCK + threadIdx.x;
    const int M = nvec - 2;   // interior vectors: v = 1 + idx, idx in [0, M)

    // ---- phase 1: d^2 partial (12 lane-contiguous float4 loads in flight) ----
    float acc = 0.0f;
    int idx = tid;
    for (; idx + 3 * T < M; idx += 4 * T) {
        float4 p[4], c[4], q[4];
        #pragma unroll
        for (int u = 0; u < 4; ++u) {
            int v = 1 + idx + u * T;
            p[u] = fv[v - 1];
            c[u] = fv[v];
            q[u] = fv[v + 1];
        }
        #pragma unroll
        for (int u = 0; u < 4; ++u)
            acc += vec_terms(p[u], c[u], q[u]);
    }
    for (; idx < M; idx += T) {
        int v = 1 + idx;
        acc += vec_terms(fv[v - 1], fv[v], fv[v + 1]);
    }
    if (tid == 0) {
        #pragma unroll
        for (int k = 0; k < 4; ++k) acc += change_term(f, k, n);
        long long j0 = n - 4;
        #pragma unroll
        for (int k = 0; k < 4; ++k) acc += change_term(f, j0 + k, n);
    }

    #pragma unroll
    for (int off = 32; off > 0; off >>= 1)
        acc += __shfl_down(acc, off, 64);
    __shared__ float smem[4];
    __shared__ float s_stot;
    __shared__ int s_timeout;
    const int lane = threadIdx.x & 63;
    const int wave = threadIdx.x >> 6;
    if (lane == 0) smem[wave] = acc;
    __syncthreads();

    // ---- device-wide barrier: arrive (release) + spin (acquire), thread 0 only ----
    if (threadIdx.x == 0) {
        float bp = smem[0] + smem[1] + smem[2] + smem[3];
        __hip_atomic_store(&g_partials[blockIdx.x], bp,
                           __ATOMIC_RELAXED, __HIP_MEMORY_SCOPE_AGENT);
        unsigned int old = __hip_atomic_fetch_add(&g_arrive, 1u,
                           __ATOMIC_RELEASE, __HIP_MEMORY_SCOPE_AGENT);
        unsigned int target = (old / (unsigned)grid + 1u) * (unsigned)grid;
        int timeout = 0;
        long long polls = 0;
        while (__hip_atomic_load(&g_arrive, __ATOMIC_ACQUIRE,
                                 __HIP_MEMORY_SCOPE_AGENT) < target) {
            __builtin_amdgcn_s_sleep(2);
            if (++polls > (4LL << 20)) { timeout = 1; break; }  // ~0.2s: co-residency failed
        }
        s_timeout = timeout;
    }
    __syncthreads();

    // ---- S: fold partials, or (timeout insurance) recompute from f ----
    float s = 0.0f;
    if (!s_timeout) {
        for (int k = threadIdx.x; k < grid; k += BLOCK)
            s += __hip_atomic_load(&g_partials[k], __ATOMIC_RELAXED,
                                   __HIP_MEMORY_SCOPE_AGENT);
    } else {
        for (int v = 1 + (int)threadIdx.x; v < 1 + M; v += BLOCK)
            s += vec_terms(fv[v - 1], fv[v], fv[v + 1]);
        if (threadIdx.x == 0) {
            #pragma unroll
            for (int k = 0; k < 4; ++k) s += change_term(f, k, n);
            long long j0 = n - 4;
            #pragma unroll
            for (int k = 0; k < 4; ++k) s += change_term(f, j0 + k, n);
        }
    }
    #pragma unroll
    for (int off = 32; off > 0; off >>= 1)
        s += __shfl_down(s, off, 64);
    if (lane == 0) smem[wave] = s;
    __syncthreads();
    if (threadIdx.x == 0) s_stot = smem[0] + smem[1] + smem[2] + smem[3];
    __syncthreads();
    const float inv = 1.0f / s_stot;

    // ---- phase 2: finalize; f re-read L3-warm; NT full-line stores ----
    idx = tid;
    for (; idx + 3 * T < M; idx += 4 * T) {
        float4 p[4], c[4], q[4];
        #pragma unroll
        for (int u = 0; u < 4; ++u) {
            int v = 1 + idx + u * T;
            p[u] = fv[v - 1];
            c[u] = fv[v];
            q[u] = fv[v + 1];
        }
        #pragma unroll
        for (int u = 0; u < 4; ++u)
            __builtin_nontemporal_store(vec_out(p[u], c[u], q[u], inv),
                                        &ov[1 + idx + u * T]);
    }
    for (; idx < M; idx += T) {
        int v = 1 + idx;
        __builtin_nontemporal_store(vec_out(fv[v - 1], fv[v], fv[v + 1], inv), &ov[v]);
    }
    if (tid == 0) {
        #pragma unroll
        for (int k = 0; k < 4; ++k) {
            float cge = change_term(f, k, n) * inv;
            out[k] = pow5(1.0f - cge) * f[k];
        }
        long long j0 = n - 4;
        #pragma unroll
        for (int k = 0; k < 4; ++k) {
            long long j = j0 + k;
            float cge = change_term(f, j, n) * inv;
            out[j] = pow5(1.0f - cge) * f[j];
        }
    }
}

extern "C" void kernel_launch(void* const* d_in, const int* in_sizes, int n_in,
                              void* d_out, int out_size, void* d_ws, size_t ws_size,
                              hipStream_t stream) {
    const float* f = (const float*)d_in[0];
    float* out = (float*)d_out;
    long long n = (long long)in_sizes[0];
    int nvec = (int)(n / 4);  // n = 2^24, divisible by 4
    (void)d_ws; (void)ws_size;

    // one-time grid sizing to guaranteed co-residency (host-side query only)
    static int grid = -1;
    if (grid < 0) {
        int dev = 0;
        (void)hipGetDevice(&dev);
        int ncu = 0;
        if (hipDeviceGetAttribute(&ncu, hipDeviceAttributeMultiprocessorCount, dev) != hipSuccess || ncu <= 0)
            ncu = 256;
        int bpc = 0;
        if (hipOccupancyMaxActiveBlocksPerMultiprocessor(&bpc, (const void*)fused_onepass, BLOCK, 0) != hipSuccess
            || bpc <= 0)
            bpc = 2;  // conservative: 2 blocks/CU is safely co-resident
        long long g = (long long)bpc * ncu;
        if (g > GRID_CAP) g = GRID_CAP;
        if (g < 1) g = 1;
        grid = (int)g;
    }

    fused_onepass<<<grid, BLOCK, 0, stream>>>(f, nvec, n, out);
}

// Round 7
// 131.827 us; speedup vs baseline: 1.7705x; 1.7705x over previous
//
#include <hip/hip_runtime.h>

// change[i] (i>=1) ∝ (g(i-3) - g(i+2))^2   with g(k)=f[k] zero-padded; change[0]=0
// out[i] = (1 - change[i]/S)^5 * f[i],  S = sum(change)
// The 1/5 conv scaling cancels in change[i]/S, so we accumulate unscaled d^2.
//
// R12: single dispatch, CONTENTION-FREE RELAXED-SYSTEM barrier.
// R8 (cg, 237us) and R11 (central atomic + release/acquire agent, 305us) show
// the barrier cost is the primitives: one contended line x 2048 serialized
// cross-XCD RMWs, plus cache-maintenance from release/acquire on non-coherent
// per-XCD L2s. Fix:
//  - ALL sync data (partials, counters, go) accessed with RELAXED +
//    SYSTEM scope -> sc0 sc1, executed/served at the coherent L3. No L2
//    invalidate/writeback ops at all; no staleness (L3 is the coherence point).
//  - ordering partial-store -> arrival via one explicit s_waitcnt(0).
//  - arrival split over 32 sub-counters on separate lines (bid&31):
//    32 parallel chains of grid/32 RMWs; last-of-sub bumps stage2; last of
//    stage2 bumps the go generation counter. ~2-3us total at grid=1024.
//  - spin: thread 0 only, relaxed-system poll of go + s_sleep(8) backoff.
//  - monotonic generations across graph replays (R11-proven); bounded spin
//    with local-recompute fallback (never hangs, always correct).
// Phases = R10's lane-contiguous loops (per-instruction coalescing), grid 1024.

#define BLOCK 256
#define GRID_CAP 1024
#define NSUB 32
#define SUB_STRIDE 16   // uints; 64B between sub-counters

typedef __attribute__((ext_vector_type(4))) float vfloat4;

__device__ unsigned int g_sub[NSUB * SUB_STRIDE];  // arrival sub-counters (monotonic)
__device__ unsigned int g_stage2 = 0u;             // completed-sub counter (monotonic)
__device__ unsigned int g_go = 0u;                 // completed-generation counter
__device__ float g_partials[GRID_CAP];

__device__ __forceinline__ float change_term(const float* __restrict__ f, long long i, long long n) {
    if (i < 1) return 0.0f;
    float a = (i >= 3)    ? f[i - 3] : 0.0f;
    float b = (i + 2 < n) ? f[i + 2] : 0.0f;
    float d = a - b;
    return d * d;
}

__device__ __forceinline__ float pow5(float t) {
    float t2 = t * t;
    float t4 = t2 * t2;
    return t4 * t;
}

// terms for vector v given p=fv[v-1], c=fv[v], q=fv[v+1]; element j=4v+k uses
// a=f[j-3], b=f[j+2]
__device__ __forceinline__ float vec_terms(float4 p, float4 c, float4 q) {
    float d0 = p.y - c.z;
    float d1 = p.z - c.w;
    float d2 = p.w - q.x;
    float d3 = c.x - q.y;
    return d0 * d0 + d1 * d1 + d2 * d2 + d3 * d3;
}

__device__ __forceinline__ vfloat4 vec_out(float4 p, float4 c, float4 q, float inv) {
    float d0 = p.y - c.z;
    float d1 = p.z - c.w;
    float d2 = p.w - q.x;
    float d3 = c.x - q.y;
    vfloat4 o;
    o.x = pow5(1.0f - d0 * d0 * inv) * c.x;
    o.y = pow5(1.0f - d1 * d1 * inv) * c.y;
    o.z = pow5(1.0f - d2 * d2 * inv) * c.z;
    o.w = pow5(1.0f - d3 * d3 * inv) * c.w;
    return o;
}

__global__ __launch_bounds__(BLOCK)
void fused_onepass(const float* __restrict__ f, int nvec, long long n,
                   float* __restrict__ out) {
    const float4* __restrict__ fv = (const float4*)f;
    vfloat4* __restrict__ ov = (vfloat4*)out;
    const int grid = (int)gridDim.x;      // multiple of NSUB (host guarantees)
    const int T = grid * BLOCK;
    const int tid = blockIdx.x * BLOCK + threadIdx.x;
    const int M = nvec - 2;   // interior vectors: v = 1 + idx, idx in [0, M)

    // ---- phase 1: d^2 partial (12 lane-contiguous float4 loads in flight) ----
    float acc = 0.0f;
    int idx = tid;
    for (; idx + 3 * T < M; idx += 4 * T) {
        float4 p[4], c[4], q[4];
        #pragma unroll
        for (int u = 0; u < 4; ++u) {
            int v = 1 + idx + u * T;
            p[u] = fv[v - 1];
            c[u] = fv[v];
            q[u] = fv[v + 1];
        }
        #pragma unroll
        for (int u = 0; u < 4; ++u)
            acc += vec_terms(p[u], c[u], q[u]);
    }
    for (; idx < M; idx += T) {
        int v = 1 + idx;
        acc += vec_terms(fv[v - 1], fv[v], fv[v + 1]);
    }
    if (tid == 0) {
        #pragma unroll
        for (int k = 0; k < 4; ++k) acc += change_term(f, k, n);
        long long j0 = n - 4;
        #pragma unroll
        for (int k = 0; k < 4; ++k) acc += change_term(f, j0 + k, n);
    }

    #pragma unroll
    for (int off = 32; off > 0; off >>= 1)
        acc += __shfl_down(acc, off, 64);
    __shared__ float smem[4];
    __shared__ float s_stot;
    __shared__ int s_timeout;
    const int lane = threadIdx.x & 63;
    const int wave = threadIdx.x >> 6;
    if (lane == 0) smem[wave] = acc;
    __syncthreads();

    // ---- device barrier: relaxed-system ops only, split arrival counters ----
    if (threadIdx.x == 0) {
        float bp = smem[0] + smem[1] + smem[2] + smem[3];
        __hip_atomic_store(&g_partials[blockIdx.x], bp,
                           __ATOMIC_RELAXED, __HIP_MEMORY_SCOPE_SYSTEM);
        __builtin_amdgcn_s_waitcnt(0);   // partial at L3 before arrival counts

        const unsigned per = (unsigned)grid / NSUB;   // arrivals per sub per gen
        unsigned old = __hip_atomic_fetch_add(&g_sub[(blockIdx.x & (NSUB - 1)) * SUB_STRIDE],
                                              1u, __ATOMIC_RELAXED, __HIP_MEMORY_SCOPE_SYSTEM);
        unsigned gen = old / per;
        if (old - gen * per == per - 1u) {            // last arrival of this sub, this gen
            unsigned old2 = __hip_atomic_fetch_add(&g_stage2, 1u,
                                __ATOMIC_RELAXED, __HIP_MEMORY_SCOPE_SYSTEM);
            if ((old2 % NSUB) == NSUB - 1u)           // last sub of this gen
                __hip_atomic_fetch_add(&g_go, 1u,
                    __ATOMIC_RELAXED, __HIP_MEMORY_SCOPE_SYSTEM);
        }

        const unsigned want = gen + 1u;
        int timeout = 0;
        long long polls = 0;
        while (__hip_atomic_load(&g_go, __ATOMIC_RELAXED,
                                 __HIP_MEMORY_SCOPE_SYSTEM) < want) {
            __builtin_amdgcn_s_sleep(8);              // ~512 cycles/poll
            if (++polls > (200LL << 10)) { timeout = 1; break; }   // ~40ms
        }
        s_timeout = timeout;
    }
    __syncthreads();

    // ---- S: fold partials (relaxed-system, L3-direct), or recompute on timeout ----
    float s = 0.0f;
    if (!s_timeout) {
        for (int k = threadIdx.x; k < grid; k += BLOCK)
            s += __hip_atomic_load(&g_partials[k], __ATOMIC_RELAXED,
                                   __HIP_MEMORY_SCOPE_SYSTEM);
    } else {
        for (int v = 1 + (int)threadIdx.x; v < 1 + M; v += BLOCK)
            s += vec_terms(fv[v - 1], fv[v], fv[v + 1]);
        if (threadIdx.x == 0) {
            #pragma unroll
            for (int k = 0; k < 4; ++k) s += change_term(f, k, n);
            long long j0 = n - 4;
            #pragma unroll
            for (int k = 0; k < 4; ++k) s += change_term(f, j0 + k, n);
        }
    }
    #pragma unroll
    for (int off = 32; off > 0; off >>= 1)
        s += __shfl_down(s, off, 64);
    if (lane == 0) smem[wave] = s;
    __syncthreads();
    if (threadIdx.x == 0) s_stot = smem[0] + smem[1] + smem[2] + smem[3];
    __syncthreads();
    const float inv = 1.0f / s_stot;

    // ---- phase 2: finalize; f re-read L3-warm; NT full-line stores ----
    idx = tid;
    for (; idx + 3 * T < M; idx += 4 * T) {
        float4 p[4], c[4], q[4];
        #pragma unroll
        for (int u = 0; u < 4; ++u) {
            int v = 1 + idx + u * T;
            p[u] = fv[v - 1];
            c[u] = fv[v];
            q[u] = fv[v + 1];
        }
        #pragma unroll
        for (int u = 0; u < 4; ++u)
            __builtin_nontemporal_store(vec_out(p[u], c[u], q[u], inv),
                                        &ov[1 + idx + u * T]);
    }
    for (; idx < M; idx += T) {
        int v = 1 + idx;
        __builtin_nontemporal_store(vec_out(fv[v - 1], fv[v], fv[v + 1], inv), &ov[v]);
    }
    if (tid == 0) {
        #pragma unroll
        for (int k = 0; k < 4; ++k) {
            float cge = change_term(f, k, n) * inv;
            out[k] = pow5(1.0f - cge) * f[k];
        }
        long long j0 = n - 4;
        #pragma unroll
        for (int k = 0; k < 4; ++k) {
            long long j = j0 + k;
            float cge = change_term(f, j, n) * inv;
            out[j] = pow5(1.0f - cge) * f[j];
        }
    }
}

extern "C" void kernel_launch(void* const* d_in, const int* in_sizes, int n_in,
                              void* d_out, int out_size, void* d_ws, size_t ws_size,
                              hipStream_t stream) {
    const float* f = (const float*)d_in[0];
    float* out = (float*)d_out;
    long long n = (long long)in_sizes[0];
    int nvec = (int)(n / 4);  // n = 2^24, divisible by 4
    (void)d_ws; (void)ws_size;

    // one-time grid sizing: co-resident, multiple of NSUB, capped at GRID_CAP
    static int grid = -1;
    if (grid < 0) {
        int dev = 0;
        (void)hipGetDevice(&dev);
        int ncu = 0;
        if (hipDeviceGetAttribute(&ncu, hipDeviceAttributeMultiprocessorCount, dev) != hipSuccess || ncu <= 0)
            ncu = 256;
        int bpc = 0;
        if (hipOccupancyMaxActiveBlocksPerMultiprocessor(&bpc, (const void*)fused_onepass, BLOCK, 0) != hipSuccess
            || bpc <= 0)
            bpc = 2;  // conservative: 2 blocks/CU is safely co-resident
        long long g = (long long)bpc * ncu;
        if (g > GRID_CAP) g = GRID_CAP;
        g -= g % NSUB;                 // multiple of NSUB for the sub-counter math
        if (g < NSUB) g = NSUB;
        grid = (int)g;
    }

    fused_onepass<<<grid, BLOCK, 0, stream>>>(f, nvec, n, out);
}

// Round 8
// 130.106 us; speedup vs baseline: 1.7939x; 1.0132x over previous
//
#include <hip/hip_runtime.h>

// change[i] (i>=1) ∝ (g(i-3) - g(i+2))^2   with g(k)=f[k] zero-padded; change[0]=0
// out[i] = (1 - change[i]/S)^5 * f[i],  S = sum(change)
// The 1/5 conv scaling cancels in change[i]/S, so we accumulate unscaled d^2.
//
// R13 = R12 (relaxed-system split-counter barrier, 50us kernel) + saturation:
//  - grid 2048 (8 blocks/CU; kernel is ~28-60 VGPR, __launch_bounds__(256,8)
//    caps at 64) -> saturate HBM. R12's 1024 grid ran at 2.7 TB/s, occ 34%.
//  - d^2 CARRIED ACROSS THE BARRIER IN REGISTERS: each thread owns exactly
//    8 vectors (static unroll, d2[8] float4 = 32 VGPR, static indexing),
//    phase 2 loads only c (1 load/vec instead of p,c,q = 3) and applies the
//    carried d^2. 3x fewer phase-2 VMEM requests.
//  - NSUB 64: 2048 arrivals = 64 parallel chains of 32 relaxed-system RMWs.
//  - co-residency guarded: occupancy query; fallback = R12-style dynamic-grid
//    kernel. Bounded spin + local-recompute insurance (never hangs).
// Measured model: harness floor ~82us of poison fills + kernel time.

#define BLOCK 256
#define RGRID 2048
#define VPT 8                 // vectors per thread at grid 2048 (covers M<=VPT*T)
#define NSUB 64
#define SUB_STRIDE 16         // uints; 64B between sub-counter lines

typedef __attribute__((ext_vector_type(4))) float vfloat4;

__device__ unsigned int g_sub[NSUB * SUB_STRIDE];  // arrival sub-counters (monotonic)
__device__ unsigned int g_stage2 = 0u;             // completed-sub counter (monotonic)
__device__ unsigned int g_go = 0u;                 // completed-generation counter
__device__ float g_partials[RGRID];

__device__ __forceinline__ float change_term(const float* __restrict__ f, long long i, long long n) {
    if (i < 1) return 0.0f;
    float a = (i >= 3)    ? f[i - 3] : 0.0f;
    float b = (i + 2 < n) ? f[i + 2] : 0.0f;
    float d = a - b;
    return d * d;
}

__device__ __forceinline__ float pow5(float t) {
    float t2 = t * t;
    float t4 = t2 * t2;
    return t4 * t;
}

__device__ __forceinline__ float vec_terms(float4 p, float4 c, float4 q) {
    float d0 = p.y - c.z;
    float d1 = p.z - c.w;
    float d2 = p.w - q.x;
    float d3 = c.x - q.y;
    return d0 * d0 + d1 * d1 + d2 * d2 + d3 * d3;
}

__device__ __forceinline__ vfloat4 vec_out(float4 p, float4 c, float4 q, float inv) {
    float d0 = p.y - c.z;
    float d1 = p.z - c.w;
    float d2 = p.w - q.x;
    float d3 = c.x - q.y;
    vfloat4 o;
    o.x = pow5(1.0f - d0 * d0 * inv) * c.x;
    o.y = pow5(1.0f - d1 * d1 * inv) * c.y;
    o.z = pow5(1.0f - d2 * d2 * inv) * c.z;
    o.w = pow5(1.0f - d3 * d3 * inv) * c.w;
    return o;
}

// shared barrier piece: store partial, arrive on split counters, spin on go.
// Returns 1 on timeout (caller recomputes S locally). thread-0-only.
__device__ __forceinline__ int barrier_arrive_wait(int bid, int grid, float bp) {
    __hip_atomic_store(&g_partials[bid], bp,
                       __ATOMIC_RELAXED, __HIP_MEMORY_SCOPE_SYSTEM);
    __builtin_amdgcn_s_waitcnt(0);   // partial visible before arrival counts

    const unsigned per = (unsigned)grid / NSUB;   // arrivals per sub per gen
    unsigned old = __hip_atomic_fetch_add(&g_sub[(bid & (NSUB - 1)) * SUB_STRIDE],
                                          1u, __ATOMIC_RELAXED, __HIP_MEMORY_SCOPE_SYSTEM);
    unsigned gen = old / per;
    if (old - gen * per == per - 1u) {            // last arrival of this sub, this gen
        unsigned old2 = __hip_atomic_fetch_add(&g_stage2, 1u,
                            __ATOMIC_RELAXED, __HIP_MEMORY_SCOPE_SYSTEM);
        if ((old2 % NSUB) == NSUB - 1u)           // last sub of this gen
            __hip_atomic_fetch_add(&g_go, 1u,
                __ATOMIC_RELAXED, __HIP_MEMORY_SCOPE_SYSTEM);
    }
    const unsigned want = gen + 1u;
    long long polls = 0;
    while (__hip_atomic_load(&g_go, __ATOMIC_RELAXED,
                             __HIP_MEMORY_SCOPE_SYSTEM) < want) {
        __builtin_amdgcn_s_sleep(8);
        if (++polls > (200LL << 10)) return 1;    // ~40ms: co-residency failed
    }
    return 0;
}

// ---------------- primary: grid=2048, d^2 carried in registers ----------------

__global__ __launch_bounds__(BLOCK, 8)
void fused_regcarry(const float* __restrict__ f, int nvec, long long n,
                    float* __restrict__ out) {
    const float4* __restrict__ fv = (const float4*)f;
    vfloat4* __restrict__ ov = (vfloat4*)out;
    const int T = RGRID * BLOCK;              // compile-time 524288
    const int tid = blockIdx.x * BLOCK + threadIdx.x;
    const int M = nvec - 2;                   // interior vectors (M <= VPT*T)

    // ---- phase 1: d^2 per owned vector, kept in registers (static idx) ----
    float4 d2[VPT];
    float acc = 0.0f;
    #pragma unroll
    for (int k = 0; k < VPT; ++k) {
        int idx = tid + k * T;
        if (idx < M) {
            int v = 1 + idx;
            float4 p = fv[v - 1], c = fv[v], q = fv[v + 1];
            float e0 = p.y - c.z;
            float e1 = p.z - c.w;
            float e2 = p.w - q.x;
            float e3 = c.x - q.y;
            d2[k].x = e0 * e0;
            d2[k].y = e1 * e1;
            d2[k].z = e2 * e2;
            d2[k].w = e3 * e3;
            acc += d2[k].x + d2[k].y + d2[k].z + d2[k].w;
        } else {
            d2[k].x = d2[k].y = d2[k].z = d2[k].w = 0.0f;
        }
    }
    if (tid == 0) {
        #pragma unroll
        for (int k = 0; k < 4; ++k) acc += change_term(f, k, n);
        long long j0 = n - 4;
        #pragma unroll
        for (int k = 0; k < 4; ++k) acc += change_term(f, j0 + k, n);
    }

    #pragma unroll
    for (int off = 32; off > 0; off >>= 1)
        acc += __shfl_down(acc, off, 64);
    __shared__ float smem[4];
    __shared__ float s_stot;
    __shared__ int s_timeout;
    const int lane = threadIdx.x & 63;
    const int wave = threadIdx.x >> 6;
    if (lane == 0) smem[wave] = acc;
    __syncthreads();

    if (threadIdx.x == 0)
        s_timeout = barrier_arrive_wait(blockIdx.x, RGRID,
                                        smem[0] + smem[1] + smem[2] + smem[3]);
    __syncthreads();

    // ---- S ----
    float s = 0.0f;
    if (!s_timeout) {
        for (int k = threadIdx.x; k < RGRID; k += BLOCK)
            s += __hip_atomic_load(&g_partials[k], __ATOMIC_RELAXED,
                                   __HIP_MEMORY_SCOPE_SYSTEM);
    } else {
        for (int v = 1 + (int)threadIdx.x; v < 1 + M; v += BLOCK)
            s += vec_terms(fv[v - 1], fv[v], fv[v + 1]);
        if (threadIdx.x == 0) {
            #pragma unroll
            for (int k = 0; k < 4; ++k) s += change_term(f, k, n);
            long long j0 = n - 4;
            #pragma unroll
            for (int k = 0; k < 4; ++k) s += change_term(f, j0 + k, n);
        }
    }
    #pragma unroll
    for (int off = 32; off > 0; off >>= 1)
        s += __shfl_down(s, off, 64);
    if (lane == 0) smem[wave] = s;
    __syncthreads();
    if (threadIdx.x == 0) s_stot = smem[0] + smem[1] + smem[2] + smem[3];
    __syncthreads();
    const float inv = 1.0f / s_stot;

    // ---- phase 2: load only c, apply carried d^2, NT full-line stores ----
    #pragma unroll
    for (int k = 0; k < VPT; ++k) {
        int idx = tid + k * T;
        if (idx < M) {
            int v = 1 + idx;
            float4 c = fv[v];
            vfloat4 o;
            o.x = pow5(1.0f - d2[k].x * inv) * c.x;
            o.y = pow5(1.0f - d2[k].y * inv) * c.y;
            o.z = pow5(1.0f - d2[k].z * inv) * c.z;
            o.w = pow5(1.0f - d2[k].w * inv) * c.w;
            __builtin_nontemporal_store(o, &ov[v]);
        }
    }
    if (tid == 0) {
        #pragma unroll
        for (int k = 0; k < 4; ++k) {
            float cge = change_term(f, k, n) * inv;
            out[k] = pow5(1.0f - cge) * f[k];
        }
        long long j0 = n - 4;
        #pragma unroll
        for (int k = 0; k < 4; ++k) {
            long long j = j0 + k;
            float cge = change_term(f, j, n) * inv;
            out[j] = pow5(1.0f - cge) * f[j];
        }
    }
}

// ---------------- fallback: dynamic grid, phase-2 rereads p,c,q (R12) ----------------

__global__ __launch_bounds__(BLOCK)
void fused_dynamic(const float* __restrict__ f, int nvec, long long n,
                   float* __restrict__ out) {
    const float4* __restrict__ fv = (const float4*)f;
    vfloat4* __restrict__ ov = (vfloat4*)out;
    const int grid = (int)gridDim.x;      // multiple of NSUB (host guarantees)
    const int T = grid * BLOCK;
    const int tid = blockIdx.x * BLOCK + threadIdx.x;
    const int M = nvec - 2;

    float acc = 0.0f;
    int idx = tid;
    for (; idx + 3 * T < M; idx += 4 * T) {
        float4 p[4], c[4], q[4];
        #pragma unroll
        for (int u = 0; u < 4; ++u) {
            int v = 1 + idx + u * T;
            p[u] = fv[v - 1];
            c[u] = fv[v];
            q[u] = fv[v + 1];
        }
        #pragma unroll
        for (int u = 0; u < 4; ++u)
            acc += vec_terms(p[u], c[u], q[u]);
    }
    for (; idx < M; idx += T) {
        int v = 1 + idx;
        acc += vec_terms(fv[v - 1], fv[v], fv[v + 1]);
    }
    if (tid == 0) {
        #pragma unroll
        for (int k = 0; k < 4; ++k) acc += change_term(f, k, n);
        long long j0 = n - 4;
        #pragma unroll
        for (int k = 0; k < 4; ++k) acc += change_term(f, j0 + k, n);
    }

    #pragma unroll
    for (int off = 32; off > 0; off >>= 1)
        acc += __shfl_down(acc, off, 64);
    __shared__ float smem[4];
    __shared__ float s_stot;
    __shared__ int s_timeout;
    const int lane = threadIdx.x & 63;
    const int wave = threadIdx.x >> 6;
    if (lane == 0) smem[wave] = acc;
    __syncthreads();

    if (threadIdx.x == 0)
        s_timeout = barrier_arrive_wait(blockIdx.x, grid,
                                        smem[0] + smem[1] + smem[2] + smem[3]);
    __syncthreads();

    float s = 0.0f;
    if (!s_timeout) {
        for (int k = threadIdx.x; k < grid; k += BLOCK)
            s += __hip_atomic_load(&g_partials[k], __ATOMIC_RELAXED,
                                   __HIP_MEMORY_SCOPE_SYSTEM);
    } else {
        for (int v = 1 + (int)threadIdx.x; v < 1 + M; v += BLOCK)
            s += vec_terms(fv[v - 1], fv[v], fv[v + 1]);
        if (threadIdx.x == 0) {
            #pragma unroll
            for (int k = 0; k < 4; ++k) s += change_term(f, k, n);
            long long j0 = n - 4;
            #pragma unroll
            for (int k = 0; k < 4; ++k) s += change_term(f, j0 + k, n);
        }
    }
    #pragma unroll
    for (int off = 32; off > 0; off >>= 1)
        s += __shfl_down(s, off, 64);
    if (lane == 0) smem[wave] = s;
    __syncthreads();
    if (threadIdx.x == 0) s_stot = smem[0] + smem[1] + smem[2] + smem[3];
    __syncthreads();
    const float inv = 1.0f / s_stot;

    idx = tid;
    for (; idx + 3 * T < M; idx += 4 * T) {
        float4 p[4], c[4], q[4];
        #pragma unroll
        for (int u = 0; u < 4; ++u) {
            int v = 1 + idx + u * T;
            p[u] = fv[v - 1];
            c[u] = fv[v];
            q[u] = fv[v + 1];
        }
        #pragma unroll
        for (int u = 0; u < 4; ++u)
            __builtin_nontemporal_store(vec_out(p[u], c[u], q[u], inv),
                                        &ov[1 + idx + u * T]);
    }
    for (; idx < M; idx += T) {
        int v = 1 + idx;
        __builtin_nontemporal_store(vec_out(fv[v - 1], fv[v], fv[v + 1], inv), &ov[v]);
    }
    if (tid == 0) {
        #pragma unroll
        for (int k = 0; k < 4; ++k) {
            float cge = change_term(f, k, n) * inv;
            out[k] = pow5(1.0f - cge) * f[k];
        }
        long long j0 = n - 4;
        #pragma unroll
        for (int k = 0; k < 4; ++k) {
            long long j = j0 + k;
            float cge = change_term(f, j, n) * inv;
            out[j] = pow5(1.0f - cge) * f[j];
        }
    }
}

extern "C" void kernel_launch(void* const* d_in, const int* in_sizes, int n_in,
                              void* d_out, int out_size, void* d_ws, size_t ws_size,
                              hipStream_t stream) {
    const float* f = (const float*)d_in[0];
    float* out = (float*)d_out;
    long long n = (long long)in_sizes[0];
    int nvec = (int)(n / 4);  // n = 2^24, divisible by 4
    (void)d_ws; (void)ws_size;

    // one-time: can fused_regcarry co-reside at RGRID blocks?  (host-side only)
    static int use_reg = -1;
    static int dyn_grid = 0;
    if (use_reg < 0) {
        int dev = 0;
        (void)hipGetDevice(&dev);
        int ncu = 0;
        if (hipDeviceGetAttribute(&ncu, hipDeviceAttributeMultiprocessorCount, dev) != hipSuccess || ncu <= 0)
            ncu = 256;
        int bpc_reg = 0;
        (void)hipOccupancyMaxActiveBlocksPerMultiprocessor(&bpc_reg, (const void*)fused_regcarry, BLOCK, 0);
        long long M = (long long)nvec - 2;
        bool cover = (long long)VPT * RGRID * BLOCK >= M;
        use_reg = (bpc_reg * ncu >= RGRID && cover) ? 1 : 0;

        int bpc_dyn = 0;
        if (hipOccupancyMaxActiveBlocksPerMultiprocessor(&bpc_dyn, (const void*)fused_dynamic, BLOCK, 0) != hipSuccess
            || bpc_dyn <= 0)
            bpc_dyn = 2;
        long long g = (long long)bpc_dyn * ncu;
        if (g > RGRID) g = RGRID;
        g -= g % NSUB;
        if (g < NSUB) g = NSUB;
        dyn_grid = (int)g;
    }

    if (use_reg)
        fused_regcarry<<<RGRID, BLOCK, 0, stream>>>(f, nvec, n, out);
    else
        fused_dynamic<<<dyn_grid, BLOCK, 0, stream>>>(f, nvec, n, out);
}

// Round 9
// 127.066 us; speedup vs baseline: 1.8369x; 1.0239x over previous
//
#include <hip/hip_runtime.h>

// change[i] (i>=1) ∝ (g(i-3) - g(i+2))^2   with g(k)=f[k] zero-padded; change[0]=0
// out[i] = (1 - change[i]/S)^5 * f[i],  S = sum(change)
// The 1/5 conv scaling cancels in change[i]/S, so we accumulate unscaled d^2.
//
// R14: 2 dispatches (timed-fastest structure: R0/R10 119-123 vs fused 130+),
// with the 3x VMEM request amplification removed via LDS stencil:
//  - each block owns a CONTIGUOUS 2048-vector chunk; stages [chunk-1 .. chunk+1]
//    (halo) into LDS with exactly ONE coalesced float4 load per vector
//    (previous kernels loaded p,c,q = 3 requests per 16B; L1-served but
//    throttled the front-end to ~half of achievable BW: 2.8/6.3 TB/s at
//    ideal traffic, occupancy 74%, VALU 8% -- classic request-rate limit).
//  - diffs computed from LDS (ds_read_b128, lane-contiguous, conflict-free);
//    zero-filled halos give the boundary semantics; only change[0] needs a
//    one-term fixup (d0 := 0 at v==0).
//  - reduce: block partial -> plain store to partials[bid] (no memset/atomic).
//  - finalize: stage f chunk (L3-warm), fold 2048 partials with shfl-only
//    reduction while ds_writes drain, ONE __syncthreads, compute + NT stores.

#define BLOCK 256
#define VPT 8
#define VPB (BLOCK * VPT)     // 2048 vectors per block, contiguous

typedef __attribute__((ext_vector_type(4))) float vfloat4;

__device__ __forceinline__ float pow5(float t) {
    float t2 = t * t;
    float t4 = t2 * t2;
    return t4 * t;
}

// stage vectors [base-1, base+VPB] into lds[0..VPB+1], zero-filled outside [0,nvec)
__device__ __forceinline__ void stage_chunk(const float4* __restrict__ fv,
                                            long long base, int nvec,
                                            float4* __restrict__ lds, int t) {
    #pragma unroll
    for (int j = 0; j <= VPT; ++j) {
        int h = t + j * BLOCK;                 // 0 .. 2303, need 0 .. VPB+1
        if (h < VPB + 2) {
            long long v = base - 1 + h;
            float4 val;
            if (v >= 0 && v < (long long)nvec) {
                val = fv[v];
            } else {
                val.x = 0.0f; val.y = 0.0f; val.z = 0.0f; val.w = 0.0f;
            }
            lds[h] = val;
        }
    }
}

__global__ __launch_bounds__(BLOCK)
void reduce_kernel(const float* __restrict__ f, int nvec,
                   float* __restrict__ partials) {
    __shared__ float4 lds[VPB + 2];
    const float4* __restrict__ fv = (const float4*)f;
    const int t = threadIdx.x;
    const long long base = (long long)blockIdx.x * VPB;

    stage_chunk(fv, base, nvec, lds, t);
    __syncthreads();

    float acc = 0.0f;
    #pragma unroll
    for (int j = 0; j < VPT; ++j) {
        int h = 1 + t + j * BLOCK;
        long long v = base + t + j * BLOCK;
        if (v < (long long)nvec) {
            float4 p = lds[h - 1], c = lds[h], q = lds[h + 1];
            float d0 = p.y - c.z;
            float d1 = p.z - c.w;
            float d2 = p.w - q.x;
            float d3 = c.x - q.y;
            if (v == 0) d0 = 0.0f;             // change[0] = 0
            acc += d0 * d0 + d1 * d1 + d2 * d2 + d3 * d3;
        }
    }

    // wave (64-lane) reduction, then 4-wave LDS fold
    #pragma unroll
    for (int off = 32; off > 0; off >>= 1)
        acc += __shfl_down(acc, off, 64);
    __shared__ float smem[4];
    const int lane = t & 63;
    const int wave = t >> 6;
    if (lane == 0) smem[wave] = acc;
    __syncthreads();
    if (t == 0)
        partials[blockIdx.x] = smem[0] + smem[1] + smem[2] + smem[3];  // plain store
}

__global__ __launch_bounds__(BLOCK)
void finalize_kernel(const float* __restrict__ f, int nvec,
                     const float* __restrict__ partials, int npart,
                     float* __restrict__ out) {
    __shared__ float4 lds[VPB + 2];
    __shared__ float smem_s[4];
    const float4* __restrict__ fv = (const float4*)f;
    vfloat4* __restrict__ ov = (vfloat4*)out;
    const int t = threadIdx.x;
    const long long base = (long long)blockIdx.x * VPB;

    // stage chunk (ds_writes in flight) ...
    stage_chunk(fv, base, nvec, lds, t);

    // ... while folding the partials (global loads + shfl only, no LDS deps)
    float s = 0.0f;
    for (int k = t; k < npart; k += BLOCK)
        s += partials[k];
    #pragma unroll
    for (int off = 32; off > 0; off >>= 1)
        s += __shfl_down(s, off, 64);
    const int lane = t & 63;
    const int wave = t >> 6;
    if (lane == 0) smem_s[wave] = s;

    __syncthreads();   // one barrier: LDS staging complete AND smem_s ready
    const float inv = 1.0f / (smem_s[0] + smem_s[1] + smem_s[2] + smem_s[3]);

    #pragma unroll
    for (int j = 0; j < VPT; ++j) {
        int h = 1 + t + j * BLOCK;
        long long v = base + t + j * BLOCK;
        if (v < (long long)nvec) {
            float4 p = lds[h - 1], c = lds[h], q = lds[h + 1];
            float d0 = p.y - c.z;
            float d1 = p.z - c.w;
            float d2 = p.w - q.x;
            float d3 = c.x - q.y;
            if (v == 0) d0 = 0.0f;             // change[0] = 0
            vfloat4 o;
            o.x = pow5(1.0f - d0 * d0 * inv) * c.x;
            o.y = pow5(1.0f - d1 * d1 * inv) * c.y;
            o.z = pow5(1.0f - d2 * d2 * inv) * c.z;
            o.w = pow5(1.0f - d3 * d3 * inv) * c.w;
            __builtin_nontemporal_store(o, &ov[v]);
        }
    }
}

extern "C" void kernel_launch(void* const* d_in, const int* in_sizes, int n_in,
                              void* d_out, int out_size, void* d_ws, size_t ws_size,
                              hipStream_t stream) {
    const float* f = (const float*)d_in[0];
    float* out = (float*)d_out;
    float* partials = (float*)d_ws;            // grid floats; 8 KB at n=2^24 (ws-proven R6/R7/R10)
    long long n = (long long)in_sizes[0];
    int nvec = (int)(n / 4);                   // n = 2^24, divisible by 4

    int grid = (nvec + VPB - 1) / VPB;         // 2048 for n=2^24

    reduce_kernel<<<grid, BLOCK, 0, stream>>>(f, nvec, partials);
    finalize_kernel<<<grid, BLOCK, 0, stream>>>(f, nvec, partials, grid, out);
}